// Round 1
// baseline (121.311 us; speedup 1.0000x reference)
//
#include <hip/hip_runtime.h>

#define NPTS 65536
#define NB_SHIFT 16   // log2(NPTS)
#define KNBR 16
#define HID 64

// ---------------- pre-pass: pos (B,3,N) -> xyzt (B,N) float4 ----------------
__global__ __launch_bounds__(256) void xyzt_kernel(const float* __restrict__ pos,
                                                   float4* __restrict__ xyzt) {
    int g = blockIdx.x * 256 + threadIdx.x;          // 0 .. B*N-1
    int b = g >> NB_SHIFT;
    int n = g & (NPTS - 1);
    const float* p = pos + (size_t)b * 3 * NPTS;
    float4 v;
    v.x = p[n];
    v.y = p[n + NPTS];
    v.z = p[n + 2 * NPTS];
    v.w = 0.f;
    xyzt[((size_t)b << NB_SHIFT) + n] = v;
}

// ---------------- main kernel ----------------
// USE_T = 1 : gather via transposed float4 table in ws
// USE_T = 0 : gather 3 scalars straight from pos (fallback, no ws needed)
template <int USE_T>
__global__ __launch_bounds__(256) void point_embed_kernel(
    const float*  __restrict__ pos,
    const float4* __restrict__ xyzt,
    const int*    __restrict__ idx,
    const float*  __restrict__ dist,
    const float*  __restrict__ W,
    const float*  __restrict__ bias,
    float*        __restrict__ out) {
    __shared__ float feat[256 * 12];   // stride 12 floats (48 B) -> 16B-aligned rows
    const int tid = threadIdx.x;

    // XCD-aware swizzle: 1024 blocks, 8 XCDs -> XCD k handles a contiguous
    // 128-block range => gather working set per XCD = 1 batch = 1 MB (fits L2).
    const int blk = ((int)blockIdx.x % 8) * 128 + ((int)blockIdx.x / 8);
    const int g = blk * 256 + tid;                    // global point id
    const int b = g >> NB_SHIFT;
    const int n = g & (NPTS - 1);

    // --- W slice for phase 2: this thread owns hidden cols 4*hq .. 4*hq+3 ---
    const int hq = tid & 15;
    float4 Wv[10];
#pragma unroll
    for (int c = 0; c < 10; ++c)
        Wv[c] = ((const float4*)(W + c * HID))[hq];
    const float4 bv = ((const float4*)bias)[hq];

    // --- phase 1: per-point feature (10 floats) ---
    const int4* iv = (const int4*)idx + (size_t)g * 4;
    int4 i0 = iv[0], i1 = iv[1], i2 = iv[2], i3 = iv[3];
    const float4* dv = (const float4*)dist + (size_t)g * 4;
    float4 d0 = dv[0], d1 = dv[1], d2 = dv[2], d3 = dv[3];
    float maxd = fmaxf(
        fmaxf(fmaxf(fmaxf(d0.x, d0.y), fmaxf(d0.z, d0.w)),
              fmaxf(fmaxf(d1.x, d1.y), fmaxf(d1.z, d1.w))),
        fmaxf(fmaxf(fmaxf(d2.x, d2.y), fmaxf(d2.z, d2.w)),
              fmaxf(fmaxf(d3.x, d3.y), fmaxf(d3.z, d3.w))));

    float cx, cy, cz;
    float mxx = -INFINITY, mxy = -INFINITY, mxz = -INFINITY;
    float mnx = INFINITY, mny = INFINITY, mnz = INFINITY;

    if (USE_T) {
        const float4* xb = xyzt + ((size_t)b << NB_SHIFT);
        float4 c = xb[n];
        cx = c.x; cy = c.y; cz = c.z;
#define GATH(J)                                   \
    {                                             \
        float4 q = xb[(J)];                       \
        mxx = fmaxf(mxx, q.x);                    \
        mxy = fmaxf(mxy, q.y);                    \
        mxz = fmaxf(mxz, q.z);                    \
        mnx = fminf(mnx, q.x);                    \
        mny = fminf(mny, q.y);                    \
        mnz = fminf(mnz, q.z);                    \
    }
        GATH(i0.x) GATH(i0.y) GATH(i0.z) GATH(i0.w)
        GATH(i1.x) GATH(i1.y) GATH(i1.z) GATH(i1.w)
        GATH(i2.x) GATH(i2.y) GATH(i2.z) GATH(i2.w)
        GATH(i3.x) GATH(i3.y) GATH(i3.z) GATH(i3.w)
#undef GATH
    } else {
        const float* px = pos + (size_t)b * 3 * NPTS;
        cx = px[n]; cy = px[n + NPTS]; cz = px[n + 2 * NPTS];
#define GATH(J)                                   \
    {                                             \
        float qx = px[(J)];                       \
        float qy = px[(J) + NPTS];                \
        float qz = px[(J) + 2 * NPTS];            \
        mxx = fmaxf(mxx, qx);                     \
        mxy = fmaxf(mxy, qy);                     \
        mxz = fmaxf(mxz, qz);                     \
        mnx = fminf(mnx, qx);                     \
        mny = fminf(mny, qy);                     \
        mnz = fminf(mnz, qz);                     \
    }
        GATH(i0.x) GATH(i0.y) GATH(i0.z) GATH(i0.w)
        GATH(i1.x) GATH(i1.y) GATH(i1.z) GATH(i1.w)
        GATH(i2.x) GATH(i2.y) GATH(i2.z) GATH(i2.w)
        GATH(i3.x) GATH(i3.y) GATH(i3.z) GATH(i3.w)
#undef GATH
    }

    float* f = feat + tid * 12;
    f[0] = cx;       f[1] = cy;       f[2] = cz;
    f[3] = mxx;      f[4] = mxy;      f[5] = mxz;
    f[6] = cx - mnx; f[7] = cy - mny; f[8] = cz - mnz;
    f[9] = maxd;     f[10] = 0.f;     f[11] = 0.f;
    __syncthreads();

    // --- phase 2: 256 points x 64 hidden, coalesced float4 stores ---
    const int prow = tid >> 4;                       // 0..15
    const size_t outbase = (size_t)blk * 256 * HID;
#pragma unroll
    for (int i = 0; i < 16; ++i) {
        const int p = i * 16 + prow;
        const float* fp = feat + p * 12;
        float4 acc = bv;
#pragma unroll
        for (int c = 0; c < 10; ++c) {
            const float fv = fp[c];
            acc.x += fv * Wv[c].x;
            acc.y += fv * Wv[c].y;
            acc.z += fv * Wv[c].z;
            acc.w += fv * Wv[c].w;
        }
        acc.x = fmaxf(acc.x, 0.f);
        acc.y = fmaxf(acc.y, 0.f);
        acc.z = fmaxf(acc.z, 0.f);
        acc.w = fmaxf(acc.w, 0.f);
        ((float4*)(out + outbase + (size_t)p * HID))[hq] = acc;
    }
}

extern "C" void kernel_launch(void* const* d_in, const int* in_sizes, int n_in,
                              void* d_out, int out_size, void* d_ws, size_t ws_size,
                              hipStream_t stream) {
    const float* pos  = (const float*)d_in[0];
    const int*   idx  = (const int*)d_in[1];
    const float* dist = (const float*)d_in[2];
    const float* W    = (const float*)d_in[3];
    const float* bias = (const float*)d_in[4];
    float* out = (float*)d_out;

    const int total   = in_sizes[0] / 3;     // B*N = 262144
    const int nblocks = total / 256;         // 1024
    const size_t need = (size_t)total * sizeof(float4);  // 16 MB

    if (ws_size >= need) {
        xyzt_kernel<<<nblocks, 256, 0, stream>>>(pos, (float4*)d_ws);
        point_embed_kernel<1><<<nblocks, 256, 0, stream>>>(
            pos, (const float4*)d_ws, idx, dist, W, bias, out);
    } else {
        point_embed_kernel<0><<<nblocks, 256, 0, stream>>>(
            pos, nullptr, idx, dist, W, bias, out);
    }
}